// Round 1
// baseline (86.547 us; speedup 1.0000x reference)
//
#include <hip/hip_runtime.h>

// IoU assigner: N anchors x M gts (3D, 6 coords). Outputs (concatenated, f32):
//   out[0:N]     assigned labels (-1 ignore, 0 neg, gt_label pos) as float
//   out[N:7N]    assigned boxes (gt box if pos, else -1.0)
//
// Bit-exactness: all IoU arithmetic via __f*_rn intrinsics (blocks FMA
// contraction), op order mirrors the jnp reference exactly.

#define MMAX 128

__global__ __launch_bounds__(256) void iou_assign_main(
    const float* __restrict__ bx, const float* __restrict__ gt,
    const int* __restrict__ gl, float* __restrict__ out_lab,
    float* __restrict__ out_bb, unsigned long long* __restrict__ slots,
    int N, int M)
{
    __shared__ float gb[MMAX][8];          // x0,y0,z0,x1,y1,z1,area,pad
    __shared__ int   sgl[MMAX];
    __shared__ unsigned long long lsl[MMAX];

    const int tid = threadIdx.x;

    // Stage gt boxes + labels into LDS.
    for (int i = tid; i < M * 6; i += 256) gb[i / 6][i % 6] = gt[i];
    if (tid < M)    sgl[tid] = gl[tid];
    if (tid < MMAX) lsl[tid] = 0ULL;
    __syncthreads();
    // Precompute gt areas: ((dx*dy)*dz), left-to-right like jnp.prod.
    if (tid < M) {
        float dx = __fsub_rn(gb[tid][3], gb[tid][0]);
        float dy = __fsub_rn(gb[tid][4], gb[tid][1]);
        float dz = __fsub_rn(gb[tid][5], gb[tid][2]);
        gb[tid][6] = __fmul_rn(__fmul_rn(dx, dy), dz);
    }
    __syncthreads();

    const int a   = blockIdx.x * 256 + tid;
    const bool act = (a < N);

    float ax0 = 0, ay0 = 0, az0 = 0, ax1 = 0, ay1 = 0, az1 = 0, a1 = 0;
    if (act) {
        const float* p = bx + (size_t)a * 6;
        ax0 = p[0]; ay0 = p[1]; az0 = p[2];
        ax1 = p[3]; ay1 = p[4]; az1 = p[5];
        a1 = __fmul_rn(__fmul_rn(__fsub_rn(ax1, ax0), __fsub_rn(ay1, ay0)),
                       __fsub_rn(az1, az0));
    }

    float best = -1.0f;   // first iteration always replaces (iou >= 0)
    int   barg = 0;

    if (act) {
        for (int g = 0; g < M; ++g) {
            float gx0 = gb[g][0], gy0 = gb[g][1], gz0 = gb[g][2];
            float gx1 = gb[g][3], gy1 = gb[g][4], gz1 = gb[g][5];
            float a2  = gb[g][6];
            float cx = fmaxf(__fsub_rn(fminf(ax1, gx1), fmaxf(ax0, gx0)), 0.0f);
            float cy = fmaxf(__fsub_rn(fminf(ay1, gy1), fmaxf(ay0, gy0)), 0.0f);
            float cz = fmaxf(__fsub_rn(fminf(az1, gz1), fmaxf(az0, gz0)), 0.0f);
            float inter = __fmul_rn(__fmul_rn(cx, cy), cz);
            float iou = 0.0f;
            if (inter > 0.0f) {
                // ((a1+a2) - inter) + 1e-7, left-to-right like the reference
                float den = __fadd_rn(__fsub_rn(__fadd_rn(a1, a2), inter), 1e-7f);
                iou = __fdiv_rn(inter, den);
                // per-gt (max over anchors, argmax = smallest anchor on ties)
                unsigned long long enc =
                    ((unsigned long long)__float_as_uint(iou) << 32) |
                    (unsigned long long)(0xFFFFFFFFu - (unsigned)a);
                atomicMax(&lsl[g], enc);
            }
            if (iou > best) { best = iou; barg = g; }  // strict >: first argmax wins
        }

        // assigned: -1 ignore; 0 if max < 0.3; barg+1 if max >= 0.7
        int assigned;
        if      (best >= 0.7f) assigned = barg + 1;
        else if (best <  0.3f) assigned = 0;
        else                   assigned = -1;

        float lab;
        if (assigned > 0) lab = (float)sgl[barg];
        else              lab = (assigned == 0) ? 0.0f : -1.0f;
        out_lab[a] = lab;

        float* ob = out_bb + (size_t)a * 6;
        if (assigned > 0) {
            ob[0] = gb[barg][0]; ob[1] = gb[barg][1]; ob[2] = gb[barg][2];
            ob[3] = gb[barg][3]; ob[4] = gb[barg][4]; ob[5] = gb[barg][5];
        } else {
            ob[0] = -1.0f; ob[1] = -1.0f; ob[2] = -1.0f;
            ob[3] = -1.0f; ob[4] = -1.0f; ob[5] = -1.0f;
        }
    }

    // Flush per-block per-gt maxima to global slots.
    __syncthreads();
    for (int g = tid; g < M; g += 256) {
        unsigned long long v = lsl[g];
        if (v) atomicMax(&slots[g], v);
    }
}

// Low-quality override: for each gt with gt_iou_max >= 0.3, its argmax anchor
// gets assigned = gt_idx+1; when several gts pick the same anchor the LARGEST
// gt index wins (mirrors the reference's .at[].max scatter).
__global__ __launch_bounds__(MMAX) void iou_override(
    const float* __restrict__ gt, const int* __restrict__ gl,
    const unsigned long long* __restrict__ slots,
    float* __restrict__ out_lab, float* __restrict__ out_bb, int M)
{
    __shared__ int s_anchor[MMAX];
    __shared__ int s_cand[MMAX];
    const int i = threadIdx.x;

    int anchor = -1, cand = 0;
    if (i < M) {
        unsigned long long v = slots[i];
        float iou = __uint_as_float((unsigned)(v >> 32));
        if (iou >= 0.3f) {
            anchor = (int)(0xFFFFFFFFu - (unsigned)(v & 0xFFFFFFFFu));
            cand   = i + 1;
        }
    }
    s_anchor[i] = anchor;
    s_cand[i]   = cand;
    __syncthreads();

    if (cand > 0) {
        bool win = true;
        for (int j = 0; j < M; ++j) {
            if (s_cand[j] > cand && s_anchor[j] == anchor) { win = false; break; }
        }
        if (win) {
            out_lab[anchor] = (float)gl[i];
            float* ob = out_bb + (size_t)anchor * 6;
            const float* gp = gt + (size_t)i * 6;
            ob[0] = gp[0]; ob[1] = gp[1]; ob[2] = gp[2];
            ob[3] = gp[3]; ob[4] = gp[4]; ob[5] = gp[5];
        }
    }
}

extern "C" void kernel_launch(void* const* d_in, const int* in_sizes, int n_in,
                              void* d_out, int out_size, void* d_ws, size_t ws_size,
                              hipStream_t stream)
{
    const float* bx = (const float*)d_in[0];
    const float* gt = (const float*)d_in[1];
    const int*   gl = (const int*)d_in[2];
    const int N = in_sizes[0] / 6;
    int M = in_sizes[1] / 6;
    if (M > MMAX) M = MMAX;

    float* out_lab = (float*)d_out;
    float* out_bb  = (float*)d_out + N;
    unsigned long long* slots = (unsigned long long*)d_ws;

    hipMemsetAsync(d_ws, 0, MMAX * sizeof(unsigned long long), stream);

    const int blocks = (N + 255) / 256;
    hipLaunchKernelGGL(iou_assign_main, dim3(blocks), dim3(256), 0, stream,
                       bx, gt, gl, out_lab, out_bb, slots, N, M);
    hipLaunchKernelGGL(iou_override, dim3(1), dim3(MMAX), 0, stream,
                       gt, gl, slots, out_lab, out_bb, M);
}